// Round 5
// baseline (163.256 us; speedup 1.0000x reference)
//
#include <hip/hip_runtime.h>

// EncoderLayer_36352603193491:
//   codes = census LBP of images [256,128,128] (zero-padded 3x3, 8 neighbors)
//   x = codes/127.5 - 1
//   thr = cumsum(normalized relu(lat)+1e-5) * 2 - 1   (8 thresholds)
//   out[b,h,w,t] = (x >= thr[t]) ? 1.0f : 0.0f        -> [256,128,128,8] f32
//
// R4 -> R5: stencil restructure. R1 vs R4 showed stores were never the
// bottleneck; the 9 branchy scalar loads/pixel were. Now: 4 px/thread,
// 3 branch-free float4 row loads + 6 wave shuffles for x-neighbors,
// boundary zeroing via cndmask (no divergent load branches at all).
// Wave = 2 full rows (32 lanes x 4 px each). Stores: 128 B/thread contiguous.

#define WN 128
#define NROWS (256 * 128)   // 32768 global rows

typedef float float4v __attribute__((ext_vector_type(4)));

__global__ __launch_bounds__(256) void lbp_glt_kernel(
    const float* __restrict__ img,
    const float* __restrict__ lat,
    float* __restrict__ out)
{
    __shared__ int s_cmin[8];
    const int tid = threadIdx.x;

    if (tid < 8) {
        // Replicate reference float32 numerics exactly (no fma contraction).
        float pos[8];
        #pragma unroll
        for (int i = 0; i < 8; ++i) {
            float v = lat[i];
            v = v > 0.0f ? v : 0.0f;          // relu
            pos[i] = __fadd_rn(v, 1e-5f);
        }
        // numpy pairwise-sum order for n == 8: ((p0+p1)+(p2+p3)) + ((p4+p5)+(p6+p7))
        float total = __fadd_rn(
            __fadd_rn(__fadd_rn(pos[0], pos[1]), __fadd_rn(pos[2], pos[3])),
            __fadd_rn(__fadd_rn(pos[4], pos[5]), __fadd_rn(pos[6], pos[7])));
        // sequential cumsum of pos[i]/total up to this lane's index
        float cum = 0.0f;
        for (int i = 0; i <= tid; ++i)
            cum = __fadd_rn(cum, __fdiv_rn(pos[i], total));
        const float thr = __fsub_rn(__fmul_rn(cum, 2.0f), 1.0f);

        // smallest integer code c in [0,256] with (c*s - 1) >= thr
        const float s = (float)(1.0 / 127.5);  // matches np.float32(1.0/127.5)
        int g = (int)ceilf((thr + 1.0f) * 127.5f);
        if (g < 0) g = 0;
        if (g > 256) g = 256;
        while (g > 0) {
            float x = __fsub_rn(__fmul_rn((float)(g - 1), s), 1.0f);
            if (x >= thr) --g; else break;
        }
        while (g < 256) {
            float x = __fsub_rn(__fmul_rn((float)g, s), 1.0f);
            if (x < thr) ++g; else break;
        }
        s_cmin[tid] = g;
    }
    __syncthreads();

    // Wave-uniform cutoffs -> SGPRs.
    int cm[8];
    #pragma unroll
    for (int t = 0; t < 8; ++t) cm[t] = __builtin_amdgcn_readfirstlane(s_cmin[t]);

    const int lane  = tid & 63;
    const int gwave = (blockIdx.x << 2) + (tid >> 6);     // global wave id
    const int row   = (gwave << 1) + (lane >> 5);         // global row [0,32768)
    const int y     = row & (WN - 1);                     // row within image
    const int xi    = (lane & 31) << 2;                   // first x of this lane

    const float* rowptr = img + ((size_t)row << 7) + xi;

    float4v mid = *(const float4v*)rowptr;
    const bool has_top = (y > 0);
    const bool has_bot = (y < WN - 1);
    // Branch-free: boundary rows load a safe (self) address, then zeroed.
    float4v top = *(const float4v*)(rowptr + (has_top ? -WN : 0));
    float4v bot = *(const float4v*)(rowptr + (has_bot ?  WN : 0));
    if (!has_top) top = (float4v){0.0f, 0.0f, 0.0f, 0.0f};
    if (!has_bot) bot = (float4v){0.0f, 0.0f, 0.0f, 0.0f};

    // Horizontal neighbors from adjacent lanes (rows are 32-lane groups;
    // cross-row leakage at lane 31/32 is zeroed by the x-edge masks).
    float lm = __shfl(mid.w, lane - 1, 64);
    float lt = __shfl(top.w, lane - 1, 64);
    float lb = __shfl(bot.w, lane - 1, 64);
    float rm = __shfl(mid.x, lane + 1, 64);
    float rt = __shfl(top.x, lane + 1, 64);
    float rb = __shfl(bot.x, lane + 1, 64);
    const bool xm = (lane & 31) != 0;    // x > 0 exists
    const bool xp = (lane & 31) != 31;   // x+4 <= 127 exists
    if (!xm) { lm = 0.0f; lt = 0.0f; lb = 0.0f; }
    if (!xp) { rm = 0.0f; rt = 0.0f; rb = 0.0f; }

    const float t6[6] = { lt, top.x, top.y, top.z, top.w, rt };
    const float m6[6] = { lm, mid.x, mid.y, mid.z, mid.w, rm };
    const float b6[6] = { lb, bot.x, bot.y, bot.z, bot.w, rb };

    float4v o[8];
    #pragma unroll
    for (int j = 0; j < 4; ++j) {
        const float c = m6[j + 1];
        const int code = (t6[j]     >= c ?   1 : 0)   // (-1,-1)
                       | (t6[j + 1] >= c ?   2 : 0)   // (-1, 0)
                       | (t6[j + 2] >= c ?   4 : 0)   // (-1, 1)
                       | (m6[j + 2] >= c ?   8 : 0)   // ( 0, 1)
                       | (b6[j + 2] >= c ?  16 : 0)   // ( 1, 1)
                       | (b6[j + 1] >= c ?  32 : 0)   // ( 1, 0)
                       | (b6[j]     >= c ?  64 : 0)   // ( 1,-1)
                       | (m6[j + 1 - 1] >= c ? 128 : 0); // ( 0,-1)
        float4v oa, ob;
        oa.x = code >= cm[0] ? 1.0f : 0.0f;
        oa.y = code >= cm[1] ? 1.0f : 0.0f;
        oa.z = code >= cm[2] ? 1.0f : 0.0f;
        oa.w = code >= cm[3] ? 1.0f : 0.0f;
        ob.x = code >= cm[4] ? 1.0f : 0.0f;
        ob.y = code >= cm[5] ? 1.0f : 0.0f;
        ob.z = code >= cm[6] ? 1.0f : 0.0f;
        ob.w = code >= cm[7] ? 1.0f : 0.0f;
        o[2 * j]     = oa;
        o[2 * j + 1] = ob;
    }

    // 128 B contiguous per thread.
    const size_t pbase = ((size_t)row << 7) + xi;
    float4v* op = (float4v*)out + (pbase << 1);
    #pragma unroll
    for (int k = 0; k < 8; ++k) op[k] = o[k];
}

extern "C" void kernel_launch(void* const* d_in, const int* in_sizes, int n_in,
                              void* d_out, int out_size, void* d_ws, size_t ws_size,
                              hipStream_t stream) {
    const float* img = (const float*)d_in[0];
    const float* lat = (const float*)d_in[1];
    float* out = (float*)d_out;

    // 32768 rows, 2 rows per wave, 4 waves per block -> 4096 blocks.
    lbp_glt_kernel<<<dim3(NROWS / 8), dim3(256), 0, stream>>>(img, lat, out);
}

// Round 6
// 153.738 us; speedup vs baseline: 1.0619x; 1.0619x over previous
//
#include <hip/hip_runtime.h>

// EncoderLayer_36352603193491:
//   codes = census LBP of images [256,128,128] (zero-padded 3x3, 8 neighbors)
//   x = codes/127.5 - 1
//   thr = cumsum(normalized relu(lat)+1e-5) * 2 - 1   (8 thresholds)
//   out[b,h,w,t] = (x >= thr[t]) ? 1.0f : 0.0f        -> [256,128,128,8] f32
//
// R5 -> R6: revert to R4 (best measured, 153.9 us). R1/R4/R5 all land within
// 154-178 us despite disjoint memory-access structures; the timed iteration is
// bound by harness poison-fill HBM drain (512 MiB ws + 128 MiB out re-poison
// per replay, ~650-900 MiB HBM traffic/iter ~ 104-145 us floor), not by this
// kernel's internals. R4 layout: one thread per pixel, codes redistributed via
// two wave shuffles so stores are fully coalesced float4s; grid-stride
// 2048 blocks x 256, 8 px/thread; regular (non-nt) stores.

#define BN 256
#define HN 128
#define WN 128
#define NPIX (BN * HN * WN)       // 4,194,304
#define NBLOCKS 2048
#define NTHREADS (NBLOCKS * 256)  // 524,288 -> 8 pixels/thread

typedef float float4v __attribute__((ext_vector_type(4)));

__global__ __launch_bounds__(256) void lbp_glt_kernel(
    const float* __restrict__ img,
    const float* __restrict__ lat,
    float* __restrict__ out)
{
    __shared__ int s_cmin[8];
    const int tid = threadIdx.x;

    if (tid < 8) {
        // Replicate reference float32 numerics exactly (no fma contraction).
        float pos[8];
        #pragma unroll
        for (int i = 0; i < 8; ++i) {
            float v = lat[i];
            v = v > 0.0f ? v : 0.0f;          // relu
            pos[i] = __fadd_rn(v, 1e-5f);
        }
        // numpy pairwise-sum order for n == 8: ((p0+p1)+(p2+p3)) + ((p4+p5)+(p6+p7))
        float total = __fadd_rn(
            __fadd_rn(__fadd_rn(pos[0], pos[1]), __fadd_rn(pos[2], pos[3])),
            __fadd_rn(__fadd_rn(pos[4], pos[5]), __fadd_rn(pos[6], pos[7])));
        // sequential cumsum of pos[i]/total up to this lane's index
        float cum = 0.0f;
        for (int i = 0; i <= tid; ++i)
            cum = __fadd_rn(cum, __fdiv_rn(pos[i], total));
        const float thr = __fsub_rn(__fmul_rn(cum, 2.0f), 1.0f);

        // smallest integer code c in [0,256] with (c*s - 1) >= thr
        const float s = (float)(1.0 / 127.5);  // matches np.float32(1.0/127.5)
        int g = (int)ceilf((thr + 1.0f) * 127.5f);
        if (g < 0) g = 0;
        if (g > 256) g = 256;
        while (g > 0) {
            float x = __fsub_rn(__fmul_rn((float)(g - 1), s), 1.0f);
            if (x >= thr) --g; else break;
        }
        while (g < 256) {
            float x = __fsub_rn(__fmul_rn((float)g, s), 1.0f);
            if (x < thr) ++g; else break;
        }
        s_cmin[tid] = g;
    }
    __syncthreads();

    const int lane = tid & 63;
    // This lane always stores threshold group (lane&1): cutoffs in registers.
    const int h4 = (lane & 1) * 4;
    const int cm0 = s_cmin[h4 + 0];
    const int cm1 = s_cmin[h4 + 1];
    const int cm2 = s_cmin[h4 + 2];
    const int cm3 = s_cmin[h4 + 3];

    const int tg = blockIdx.x * 256 + tid;   // global thread id
    const int srcA = lane >> 1;              // shuffle sources (wave-relative)
    const int srcB = 32 + (lane >> 1);

    #pragma unroll 2
    for (int it = 0; it < NPIX / NTHREADS; ++it) {
        const int p = it * NTHREADS + tg;    // flat pixel index, < 2^22
        const int x = p & (WN - 1);
        const int y = (p >> 7) & (HN - 1);

        const float* base = img + (size_t)p;
        const float c = base[0];

        const bool ym = (y > 0), yp = (y < HN - 1);
        const bool xm = (x > 0), xp = (x < WN - 1);

        const float v_tl = (ym && xm) ? base[-WN - 1] : 0.0f;
        const float v_tc = ym         ? base[-WN]     : 0.0f;
        const float v_tr = (ym && xp) ? base[-WN + 1] : 0.0f;
        const float v_r  = xp         ? base[1]       : 0.0f;
        const float v_br = (yp && xp) ? base[WN + 1]  : 0.0f;
        const float v_bc = yp         ? base[WN]      : 0.0f;
        const float v_bl = (yp && xm) ? base[WN - 1]  : 0.0f;
        const float v_l  = xm         ? base[-1]      : 0.0f;

        const int code = (v_tl >= c ?   1 : 0)
                       | (v_tc >= c ?   2 : 0)
                       | (v_tr >= c ?   4 : 0)
                       | (v_r  >= c ?   8 : 0)
                       | (v_br >= c ?  16 : 0)
                       | (v_bc >= c ?  32 : 0)
                       | (v_bl >= c ?  64 : 0)
                       | (v_l  >= c ? 128 : 0);

        // Redistribute codes so the wave's 128 output chunks are stored
        // contiguously: chunk cbase+lane needs code of pixel pbase+(lane>>1),
        // chunk cbase+64+lane needs code of pixel pbase+32+(lane>>1).
        const int codeA = __shfl(code, srcA, 64);
        const int codeB = __shfl(code, srcB, 64);

        float4v oA, oB;
        oA.x = codeA >= cm0 ? 1.0f : 0.0f;
        oA.y = codeA >= cm1 ? 1.0f : 0.0f;
        oA.z = codeA >= cm2 ? 1.0f : 0.0f;
        oA.w = codeA >= cm3 ? 1.0f : 0.0f;
        oB.x = codeB >= cm0 ? 1.0f : 0.0f;
        oB.y = codeB >= cm1 ? 1.0f : 0.0f;
        oB.z = codeB >= cm2 ? 1.0f : 0.0f;
        oB.w = codeB >= cm3 ? 1.0f : 0.0f;

        const size_t cbase = 2 * (size_t)(p & ~63);   // wave's first chunk
        float4v* op = (float4v*)out + cbase;
        op[lane]      = oA;
        op[64 + lane] = oB;
    }
}

extern "C" void kernel_launch(void* const* d_in, const int* in_sizes, int n_in,
                              void* d_out, int out_size, void* d_ws, size_t ws_size,
                              hipStream_t stream) {
    const float* img = (const float*)d_in[0];
    const float* lat = (const float*)d_in[1];
    float* out = (float*)d_out;

    lbp_glt_kernel<<<dim3(NBLOCKS), dim3(256), 0, stream>>>(img, lat, out);
}